// Round 6
// baseline (796.644 us; speedup 1.0000x reference)
//
#include <hip/hip_runtime.h>

typedef _Float16 f16;
typedef _Float16 f16x8 __attribute__((ext_vector_type(8)));
typedef float f32x4 __attribute__((ext_vector_type(4)));

#define CIN 28
#define TT 8
#define HW 16384

// gate pre-scales folded into weights: i,f,o rows scaled by -log2e so
// exp2(acc)=e^{-x}, sig(x)=1/(1+E); g rows scaled by +2log2e so tanh=(E-1)/(E+1)
#define S_SIG  (-1.44269504088896341f)
#define S_TANH ( 2.88539008177792681f)

// workspace layout (bytes) — weights stored in FRAGMENT ORDER so each wave's
// per-step reload is a fully-coalesced 1KB global_load_dwordx4 burst (L2-hot).
#define WS_WXF    0        // f16 [wv*4+P][lane][8]            16KB
#define WS_WHH1F  16384    // f16 [(wv*4+P)*2+half][lane][8]   32KB
#define WS_W21F   49152    // 32KB
#define WS_WHH2F  81920    // 32KB
#define WS_BX     114688   // f32 [256]
#define WS_B2     115712   // f32 [256]
#define WS_WH     116736   // f32 [64]
#define WS_BH     116992   // f32 [1]

// Fused LSTM activation: 5 exp2 + 2 rcp (f-gate rcp merged into the i*g rcp:
// r = rcp(F*A*G); 1/F = r*A*G; 1/(A*G) = r*F).
__device__ __forceinline__ float lstm_act(float gi, float gf, float gg, float go,
                                          float& c) {
  const float Ei = __builtin_amdgcn_exp2f(gi);
  const float Ef = __builtin_amdgcn_exp2f(gf);
  const float Eg = __builtin_amdgcn_exp2f(gg);
  const float Eo = __builtin_amdgcn_exp2f(go);
  const float F  = 1.f + Ef;
  const float AG = (1.f + Ei) * (1.f + Eg);
  const float r  = __builtin_amdgcn_rcpf(F * AG);
  const float cn = __builtin_fmaf(c, r * AG, (Eg - 1.f) * (r * F));
  c = cn;
  const float Ec  = __builtin_amdgcn_exp2f(cn * S_TANH);
  const float roc = __builtin_amdgcn_rcpf((1.f + Eo) * (1.f + Ec));
  return (Ec - 1.f) * roc;
}

// Parallel prep: 256 blocks (one per gate row g) x 64 threads (one per col k).
// Writes weights in fragment order: P=g>>6, wv=(g>>4)&3, cl=g&15;
// half=k>>5, qd=(k>>3)&3, j=k&7; lane=qd*16+cl.
__global__ __launch_bounds__(64) void prep_kernel(
    const float* __restrict__ W_red, const float* __restrict__ b_red,
    const float* __restrict__ Wih1, const float* __restrict__ Whh1,
    const float* __restrict__ bih1, const float* __restrict__ bhh1,
    const float* __restrict__ Wc1,  const float* __restrict__ bc1,
    const float* __restrict__ Wih2, const float* __restrict__ Whh2,
    const float* __restrict__ bih2, const float* __restrict__ bhh2,
    const float* __restrict__ Wc2,  const float* __restrict__ bc2,
    const float* __restrict__ W_head, const float* __restrict__ b_head,
    unsigned char* __restrict__ ws)
{
  const int g = blockIdx.x;    // 0..255 gate row
  const int k = threadIdx.x;   // 0..63 col
  const int P  = g >> 6, wvv = (g >> 4) & 3, cl = g & 15;
  const int half = k >> 5, qd = (k >> 3) & 3, j = k & 7;
  const int lane = qd * 16 + cl;

  f16* WXF   = (f16*)(ws + WS_WXF);
  f16* WHH1F = (f16*)(ws + WS_WHH1F);
  f16* W21F  = (f16*)(ws + WS_W21F);
  f16* WHH2F = (f16*)(ws + WS_WHH2F);
  float* BX  = (float*)(ws + WS_BX);
  float* B2  = (float*)(ws + WS_B2);
  float* WHp = (float*)(ws + WS_WH);
  float* BHp = (float*)(ws + WS_BH);

  const float sc = (P == 2) ? S_TANH : S_SIG;  // g-gate rows use tanh scale

  // Wx[g][k] = Wih1[g,:] @ W_red[:,k]  (k < CIN), + u/v denorm fold
  float wxv = 0.f;
  if (k < CIN) {
    float s = 0.f;
    for (int r = 0; r < 24; ++r) s += Wih1[g*24 + r] * W_red[r*28 + k];
    wxv = s;
  }
  const float wx11 = __shfl(wxv, 11, 64);
  const float wx12 = __shfl(wxv, 12, 64);
  if (k == 11) wxv *= 0.15f;   // SD_U
  if (k == 12) wxv *= 0.12f;   // SD_V
  if (k < 32)
    WXF[((wvv*4 + P)*64 + lane)*8 + j] = (f16)(wxv * sc);

  const int fidx = (((wvv*4 + P)*2 + half)*64 + lane)*8 + j;
  WHH1F[fidx] = (f16)(Whh1[g*64 + k] * sc);
  WHH2F[fidx] = (f16)(Whh2[g*64 + k] * sc);
  {
    float s = 0.f;
    for (int m = 0; m < 64; ++m) s += Wih2[g*64 + m] * Wc1[m*64 + k];
    W21F[fidx] = (f16)(s * sc);
  }

  if (k == 0) {
    float bx = bih1[g] + bhh1[g];
    for (int r = 0; r < 24; ++r) bx += Wih1[g*24 + r] * b_red[r];
    bx += wx11 * 0.02f + wx12 * (-0.01f);   // MU_U, MU_V
    BX[g] = bx * sc;
    float b2v = bih2[g] + bhh2[g];
    for (int m = 0; m < 64; ++m) b2v += Wih2[g*64 + m] * bc1[m];
    B2[g] = b2v * sc;
  }
  if (g == 0) {
    float s = 0.f;
    for (int m = 0; m < 64; ++m) s += W_head[m] * Wc2[m*64 + k];
    WHp[k] = s;
    if (k == 0) {
      float s2 = b_head[0];
      for (int m = 0; m < 64; ++m) s2 += W_head[m] * bc2[m];
      BHp[0] = s2;
    }
  }
}

// 64 pixels/block, 4 waves; wave w owns hidden cols [16w,16w+16) x 4 gates.
// ALL weight fragments are TRANSIENT: reloaded from L2-hot ws every step
// (frag-ordered, coalesced), pipelined under the activation phases. This
// drops peak live regs to ~150 -> 3 waves/SIMD (waves_per_eu(3), 168-reg cap).
// Pointer laundering (asm "+s") defeats LICM re-hoisting the invariant loads;
// sched_barrier(0) keeps batch live ranges from overlapping.
__global__ __launch_bounds__(256)
__attribute__((amdgpu_waves_per_eu(3)))
void convlstm_main(
    const float* __restrict__ x, const unsigned char* __restrict__ ws,
    float* __restrict__ out)
{
  __shared__ __align__(16) f16 xs[2][64 * 40];       // [pixel][ch], stride 40
  __shared__ __align__(16) f16 h1buf[2][64 * 72];    // [pixel][hid], stride 72
  __shared__ __align__(16) f16 h2buf[2][64 * 72];

  const int tid  = threadIdx.x;
  const int lane = tid & 63;
  const int wv   = tid >> 6;
  const int cl   = lane & 15;
  const int qd   = lane >> 4;

  // per-thread f16x8 indices into the frag areas
  const int wx_i  = (wv*4)*64 + lane;    // + P*64
  const int hh_i  = wv*512 + lane;       // + P*128 + half*64

  const float* BX = (const float*)(ws + WS_BX);
  const float* B2 = (const float*)(ws + WS_B2);
  float bxr[4], b2r[4];
#pragma unroll
  for (int P = 0; P < 4; ++P) {
    bxr[P] = BX[64*P + 16*wv + cl];
    b2r[P] = B2[64*P + 16*wv + cl];
  }

  // zero t=0 h buffers
  {
    unsigned* z1 = (unsigned*)&h1buf[0][0];
    unsigned* z2 = (unsigned*)&h2buf[0][0];
#pragma unroll
    for (int i = tid; i < 2304; i += 256) { z1[i] = 0u; z2[i] = 0u; }
  }

  const int gpix = blockIdx.x * 64;
  const float* xb = x + (size_t)(gpix >> 14) * (TT * CIN * HW) + (gpix & (HW - 1));

  const int sp = lane;        // staging pixel
  const int cb = wv * 8;      // staging channel base

  // stage x_0
  {
    f16x8 v;
#pragma unroll
    for (int j = 0; j < 8; ++j) {
      const int ch = cb + j;
      v[j] = (ch < CIN) ? (f16)xb[ch*HW + sp] : (f16)0.f;
    }
    *(f16x8*)(&xs[0][sp*40 + cb]) = v;
  }
  __syncthreads();

  float c1s[4][4], c2s[4][4];
#pragma unroll
  for (int a = 0; a < 4; ++a)
#pragma unroll
    for (int b = 0; b < 4; ++b) { c1s[a][b] = 0.f; c2s[a][b] = 0.f; }

  // preload batch1 (wx + whh1) for t=0
  f16x8 wxf[4], whh1f[4][2];
  {
    const unsigned char* wsl = ws;
    asm volatile("" : "+s"(wsl));
    const f16x8* wxB = (const f16x8*)(wsl + WS_WXF);
    const f16x8* h1B = (const f16x8*)(wsl + WS_WHH1F);
#pragma unroll
    for (int P = 0; P < 4; ++P) {
      wxf[P]      = wxB[wx_i + P*64];
      whh1f[P][0] = h1B[hh_i + P*128];
      whh1f[P][1] = h1B[hh_i + P*128 + 64];
    }
  }

#pragma unroll 1
  for (int t = 0; t < TT; ++t) {
    // ---- prefetch x_{t+1} into registers ----
    float xr[8];
    if (t + 1 < TT) {
      const float* xt = xb + (size_t)(t + 1) * (CIN * HW);
#pragma unroll
      for (int j = 0; j < 8; ++j) {
        const int ch = cb + j;
        xr[j] = (ch < CIN) ? xt[ch*HW + sp] : 0.f;
      }
    }

    const f16* xsr = xs[t & 1];
    const f16* h1r = h1buf[t & 1];
    const f16* h2r = h2buf[t & 1];
    f16* h1w = h1buf[(t + 1) & 1];
    f16* h2w = h2buf[(t + 1) & 1];

    // ---- phase A: layer-1 gates = Whh1*h1 + Wx*x + b, act1, h1w store ----
#pragma unroll
    for (int mb = 0; mb < 4; ++mb) {
      const int p = 16*mb + cl;
      const f16x8 ax  = *(const f16x8*)(xsr + p*40 + qd*8);
      const f16x8 ah0 = *(const f16x8*)(h1r + p*72 + qd*8);
      const f16x8 ah1 = *(const f16x8*)(h1r + p*72 + 32 + qd*8);
      f32x4 acc[4];
#pragma unroll
      for (int P = 0; P < 4; ++P) {
        acc[P] = (f32x4){ bxr[P], bxr[P], bxr[P], bxr[P] };
        acc[P] = __builtin_amdgcn_mfma_f32_16x16x32_f16(ah0, whh1f[P][0], acc[P], 0, 0, 0);
        acc[P] = __builtin_amdgcn_mfma_f32_16x16x32_f16(ah1, whh1f[P][1], acc[P], 0, 0, 0);
        acc[P] = __builtin_amdgcn_mfma_f32_16x16x32_f16(ax,  wxf[P],      acc[P], 0, 0, 0);
      }
#pragma unroll
      for (int r = 0; r < 4; ++r) {
        const float hn = lstm_act(acc[0][r], acc[1][r], acc[2][r], acc[3][r],
                                  c1s[mb][r]);
        h1w[(16*mb + 4*qd + r)*72 + 16*wv + cl] = (f16)hn;
      }
    }

    // ---- batch2 loads (w21 + whh2): after batch1's last use ----
    __builtin_amdgcn_sched_barrier(0);
    f16x8 w21f[4][2], whh2f[4][2];
    {
      const unsigned char* wsl = ws;
      asm volatile("" : "+s"(wsl));
      const f16x8* w21B = (const f16x8*)(wsl + WS_W21F);
      const f16x8* w22B = (const f16x8*)(wsl + WS_WHH2F);
#pragma unroll
      for (int P = 0; P < 4; ++P) {
        w21f[P][0]  = w21B[hh_i + P*128];
        w21f[P][1]  = w21B[hh_i + P*128 + 64];
        whh2f[P][0] = w22B[hh_i + P*128];
        whh2f[P][1] = w22B[hh_i + P*128 + 64];
      }
    }

    // ---- store prefetched x_{t+1} ----
    if (t + 1 < TT) {
      f16* xsw = xs[(t + 1) & 1];
      f16x8 v;
#pragma unroll
      for (int j = 0; j < 8; ++j) v[j] = (f16)xr[j];
      *(f16x8*)(xsw + sp*40 + cb) = v;
    }
    __syncthreads();

    // ---- phase B: layer-2 gates = W21*h1_new + Whh2*h2 + b, act2 ----
#pragma unroll
    for (int mb = 0; mb < 4; ++mb) {
      const int p = 16*mb + cl;
      const f16x8 an0 = *(const f16x8*)(h1w + p*72 + qd*8);
      const f16x8 an1 = *(const f16x8*)(h1w + p*72 + 32 + qd*8);
      const f16x8 a20 = *(const f16x8*)(h2r + p*72 + qd*8);
      const f16x8 a21 = *(const f16x8*)(h2r + p*72 + 32 + qd*8);
      f32x4 acc[4];
#pragma unroll
      for (int P = 0; P < 4; ++P) {
        acc[P] = (f32x4){ b2r[P], b2r[P], b2r[P], b2r[P] };
        acc[P] = __builtin_amdgcn_mfma_f32_16x16x32_f16(an0, w21f[P][0],  acc[P], 0, 0, 0);
        acc[P] = __builtin_amdgcn_mfma_f32_16x16x32_f16(an1, w21f[P][1],  acc[P], 0, 0, 0);
        acc[P] = __builtin_amdgcn_mfma_f32_16x16x32_f16(a20, whh2f[P][0], acc[P], 0, 0, 0);
        acc[P] = __builtin_amdgcn_mfma_f32_16x16x32_f16(a21, whh2f[P][1], acc[P], 0, 0, 0);
      }
#pragma unroll
      for (int r = 0; r < 4; ++r) {
        const float hn = lstm_act(acc[0][r], acc[1][r], acc[2][r], acc[3][r],
                                  c2s[mb][r]);
        h2w[(16*mb + 4*qd + r)*72 + 16*wv + cl] = (f16)hn;
      }
    }

    // ---- reload batch1 for t+1 (hidden under act2 latency) ----
    __builtin_amdgcn_sched_barrier(0);
    if (t + 1 < TT) {
      const unsigned char* wsl = ws;
      asm volatile("" : "+s"(wsl));
      const f16x8* wxB = (const f16x8*)(wsl + WS_WXF);
      const f16x8* h1B = (const f16x8*)(wsl + WS_WHH1F);
#pragma unroll
      for (int P = 0; P < 4; ++P) {
        wxf[P]      = wxB[wx_i + P*64];
        whh1f[P][0] = h1B[hh_i + P*128];
        whh1f[P][1] = h1B[hh_i + P*128 + 64];
      }
    }
    __syncthreads();
  }

  // ---- head epilogue: out[p] = bhead + sum_k h2[p][k] * wh[k] ----
  if (tid < 64) {
    const float* wh = (const float*)(ws + WS_WH);
    const f16* row = &h2buf[0][tid * 72];   // final h2 lives in buffer 0
    float s = *((const float*)(ws + WS_BH));
#pragma unroll
    for (int k = 0; k < 64; ++k) s += (float)row[k] * wh[k];
    out[gpix + tid] = s;
  }
}

extern "C" void kernel_launch(void* const* d_in, const int* in_sizes, int n_in,
                              void* d_out, int out_size, void* d_ws, size_t ws_size,
                              hipStream_t stream) {
  const float* x      = (const float*)d_in[0];
  const float* W_red  = (const float*)d_in[1];
  const float* b_red  = (const float*)d_in[2];
  const float* Wih1   = (const float*)d_in[3];
  const float* Whh1   = (const float*)d_in[4];
  const float* bih1   = (const float*)d_in[5];
  const float* bhh1   = (const float*)d_in[6];
  const float* Wc1    = (const float*)d_in[7];
  const float* bc1    = (const float*)d_in[8];
  const float* Wih2   = (const float*)d_in[9];
  const float* Whh2   = (const float*)d_in[10];
  const float* bih2   = (const float*)d_in[11];
  const float* bhh2   = (const float*)d_in[12];
  const float* Wc2    = (const float*)d_in[13];
  const float* bc2    = (const float*)d_in[14];
  const float* W_head = (const float*)d_in[15];
  const float* b_head = (const float*)d_in[16];

  prep_kernel<<<256, 64, 0, stream>>>(W_red, b_red, Wih1, Whh1, bih1, bhh1,
                                      Wc1, bc1, Wih2, Whh2, bih2, bhh2,
                                      Wc2, bc2, W_head, b_head,
                                      (unsigned char*)d_ws);
  convlstm_main<<<2048, 256, 0, stream>>>(x, (const unsigned char*)d_ws,
                                          (float*)d_out);
}

// Round 7
// 793.712 us; speedup vs baseline: 1.0037x; 1.0037x over previous
//
#include <hip/hip_runtime.h>

typedef _Float16 f16;
typedef _Float16 f16x8 __attribute__((ext_vector_type(8)));
typedef float f32x4 __attribute__((ext_vector_type(4)));

#define CIN 28
#define TT 8
#define HW 16384

// gate pre-scales folded into weights: i,f,o rows scaled by -log2e so
// exp2(acc)=e^{-x}, sig(x)=1/(1+E); g rows scaled by +2log2e so tanh=(E-1)/(E+1)
#define S_SIG  (-1.44269504088896341f)
#define S_TANH ( 2.88539008177792681f)

// workspace layout (bytes) — weights stored in FRAGMENT ORDER so each wave's
// per-step reload is a fully-coalesced 1KB global_load_dwordx4 burst (L2-hot).
#define WS_WXF    0        // f16 [wv*4+P][lane][8]            16KB
#define WS_WHH1F  16384    // f16 [(wv*4+P)*2+half][lane][8]   32KB
#define WS_W21F   49152    // 32KB
#define WS_WHH2F  81920    // 32KB
#define WS_BX     114688   // f32 [256]
#define WS_B2     115712   // f32 [256]
#define WS_WH     116736   // f32 [64]
#define WS_BH     116992   // f32 [1]

// Fused LSTM activation: 5 exp2 + 2 rcp (f-gate rcp merged into the i*g rcp:
// r = rcp(F*A*G); 1/F = r*A*G; 1/(A*G) = r*F).
__device__ __forceinline__ float lstm_act(float gi, float gf, float gg, float go,
                                          float& c) {
  const float Ei = __builtin_amdgcn_exp2f(gi);
  const float Ef = __builtin_amdgcn_exp2f(gf);
  const float Eg = __builtin_amdgcn_exp2f(gg);
  const float Eo = __builtin_amdgcn_exp2f(go);
  const float F  = 1.f + Ef;
  const float AG = (1.f + Ei) * (1.f + Eg);
  const float r  = __builtin_amdgcn_rcpf(F * AG);
  const float cn = __builtin_fmaf(c, r * AG, (Eg - 1.f) * (r * F));
  c = cn;
  const float Ec  = __builtin_amdgcn_exp2f(cn * S_TANH);
  const float roc = __builtin_amdgcn_rcpf((1.f + Eo) * (1.f + Ec));
  return (Ec - 1.f) * roc;
}

// Parallel prep: 256 blocks (one per gate row g) x 64 threads (one per col k).
// Writes weights in fragment order: P=g>>6, wv=(g>>4)&3, cl=g&15;
// half=k>>5, qd=(k>>3)&3, j=k&7; lane=qd*16+cl.
__global__ __launch_bounds__(64) void prep_kernel(
    const float* __restrict__ W_red, const float* __restrict__ b_red,
    const float* __restrict__ Wih1, const float* __restrict__ Whh1,
    const float* __restrict__ bih1, const float* __restrict__ bhh1,
    const float* __restrict__ Wc1,  const float* __restrict__ bc1,
    const float* __restrict__ Wih2, const float* __restrict__ Whh2,
    const float* __restrict__ bih2, const float* __restrict__ bhh2,
    const float* __restrict__ Wc2,  const float* __restrict__ bc2,
    const float* __restrict__ W_head, const float* __restrict__ b_head,
    unsigned char* __restrict__ ws)
{
  const int g = blockIdx.x;    // 0..255 gate row
  const int k = threadIdx.x;   // 0..63 col
  const int P  = g >> 6, wvv = (g >> 4) & 3, cl = g & 15;
  const int half = k >> 5, qd = (k >> 3) & 3, j = k & 7;
  const int lane = qd * 16 + cl;

  f16* WXF   = (f16*)(ws + WS_WXF);
  f16* WHH1F = (f16*)(ws + WS_WHH1F);
  f16* W21F  = (f16*)(ws + WS_W21F);
  f16* WHH2F = (f16*)(ws + WS_WHH2F);
  float* BX  = (float*)(ws + WS_BX);
  float* B2  = (float*)(ws + WS_B2);
  float* WHp = (float*)(ws + WS_WH);
  float* BHp = (float*)(ws + WS_BH);

  const float sc = (P == 2) ? S_TANH : S_SIG;  // g-gate rows use tanh scale

  // Wx[g][k] = Wih1[g,:] @ W_red[:,k]  (k < CIN), + u/v denorm fold
  float wxv = 0.f;
  if (k < CIN) {
    float s = 0.f;
    for (int r = 0; r < 24; ++r) s += Wih1[g*24 + r] * W_red[r*28 + k];
    wxv = s;
  }
  const float wx11 = __shfl(wxv, 11, 64);
  const float wx12 = __shfl(wxv, 12, 64);
  if (k == 11) wxv *= 0.15f;   // SD_U
  if (k == 12) wxv *= 0.12f;   // SD_V
  if (k < 32)
    WXF[((wvv*4 + P)*64 + lane)*8 + j] = (f16)(wxv * sc);

  const int fidx = (((wvv*4 + P)*2 + half)*64 + lane)*8 + j;
  WHH1F[fidx] = (f16)(Whh1[g*64 + k] * sc);
  WHH2F[fidx] = (f16)(Whh2[g*64 + k] * sc);
  {
    float s = 0.f;
    for (int m = 0; m < 64; ++m) s += Wih2[g*64 + m] * Wc1[m*64 + k];
    W21F[fidx] = (f16)(s * sc);
  }

  if (k == 0) {
    float bx = bih1[g] + bhh1[g];
    for (int r = 0; r < 24; ++r) bx += Wih1[g*24 + r] * b_red[r];
    bx += wx11 * 0.02f + wx12 * (-0.01f);   // MU_U, MU_V
    BX[g] = bx * sc;
    float b2v = bih2[g] + bhh2[g];
    for (int m = 0; m < 64; ++m) b2v += Wih2[g*64 + m] * bc1[m];
    B2[g] = b2v * sc;
  }
  if (g == 0) {
    float s = 0.f;
    for (int m = 0; m < 64; ++m) s += W_head[m] * Wc2[m*64 + k];
    WHp[k] = s;
    if (k == 0) {
      float s2 = b_head[0];
      for (int m = 0; m < 64; ++m) s2 += W_head[m] * bc2[m];
      BHp[0] = s2;
    }
  }
}

// 64 pixels/block, 4 waves; wave w owns hidden cols [16w,16w+16) x 4 gates.
// ALL weight fragments TRANSIENT: reloaded from L2-hot ws every step
// (frag-ordered, coalesced), pipelined under the activation phases.
// waves_per_eu(3,3): PIN allocator to exactly 3 waves/EU (168-reg budget).
// Round-6 failure: waves_per_eu(3) (min only) let the occupancy heuristic
// allocate 84 VGPRs against a ~150-reg live set -> 1.8 GB scratch spill.
// Pointer laundering (asm "+s") defeats LICM re-hoisting invariant loads;
// sched_barrier(0) keeps batch live ranges from overlapping.
__global__ __launch_bounds__(256)
__attribute__((amdgpu_waves_per_eu(3, 3)))
void convlstm_main(
    const float* __restrict__ x, const unsigned char* __restrict__ ws,
    float* __restrict__ out)
{
  __shared__ __align__(16) f16 xs[2][64 * 40];       // [pixel][ch], stride 40
  __shared__ __align__(16) f16 h1buf[2][64 * 72];    // [pixel][hid], stride 72
  __shared__ __align__(16) f16 h2buf[2][64 * 72];

  const int tid  = threadIdx.x;
  const int lane = tid & 63;
  const int wv   = tid >> 6;
  const int cl   = lane & 15;
  const int qd   = lane >> 4;

  // per-thread f16x8 indices into the frag areas
  const int wx_i  = (wv*4)*64 + lane;    // + P*64
  const int hh_i  = wv*512 + lane;       // + P*128 + half*64

  const float* BX = (const float*)(ws + WS_BX);
  const float* B2 = (const float*)(ws + WS_B2);
  float bxr[4], b2r[4];
#pragma unroll
  for (int P = 0; P < 4; ++P) {
    bxr[P] = BX[64*P + 16*wv + cl];
    b2r[P] = B2[64*P + 16*wv + cl];
  }

  // zero t=0 h buffers
  {
    unsigned* z1 = (unsigned*)&h1buf[0][0];
    unsigned* z2 = (unsigned*)&h2buf[0][0];
#pragma unroll
    for (int i = tid; i < 2304; i += 256) { z1[i] = 0u; z2[i] = 0u; }
  }

  const int gpix = blockIdx.x * 64;
  const float* xb = x + (size_t)(gpix >> 14) * (TT * CIN * HW) + (gpix & (HW - 1));

  const int sp = lane;        // staging pixel
  const int cb = wv * 8;      // staging channel base

  // stage x_0
  {
    f16x8 v;
#pragma unroll
    for (int j = 0; j < 8; ++j) {
      const int ch = cb + j;
      v[j] = (ch < CIN) ? (f16)xb[ch*HW + sp] : (f16)0.f;
    }
    *(f16x8*)(&xs[0][sp*40 + cb]) = v;
  }
  __syncthreads();

  float c1s[4][4], c2s[4][4];
#pragma unroll
  for (int a = 0; a < 4; ++a)
#pragma unroll
    for (int b = 0; b < 4; ++b) { c1s[a][b] = 0.f; c2s[a][b] = 0.f; }

  // preload batch1 (wx + whh1) for t=0
  f16x8 wxf[4], whh1f[4][2];
  {
    const unsigned char* wsl = ws;
    asm volatile("" : "+s"(wsl));
    const f16x8* wxB = (const f16x8*)(wsl + WS_WXF);
    const f16x8* h1B = (const f16x8*)(wsl + WS_WHH1F);
#pragma unroll
    for (int P = 0; P < 4; ++P) {
      wxf[P]      = wxB[wx_i + P*64];
      whh1f[P][0] = h1B[hh_i + P*128];
      whh1f[P][1] = h1B[hh_i + P*128 + 64];
    }
  }

#pragma unroll 1
  for (int t = 0; t < TT; ++t) {
    // ---- prefetch x_{t+1} into registers ----
    float xr[8];
    if (t + 1 < TT) {
      const float* xt = xb + (size_t)(t + 1) * (CIN * HW);
#pragma unroll
      for (int j = 0; j < 8; ++j) {
        const int ch = cb + j;
        xr[j] = (ch < CIN) ? xt[ch*HW + sp] : 0.f;
      }
    }

    const f16* xsr = xs[t & 1];
    const f16* h1r = h1buf[t & 1];
    const f16* h2r = h2buf[t & 1];
    f16* h1w = h1buf[(t + 1) & 1];
    f16* h2w = h2buf[(t + 1) & 1];

    // ---- phase A: layer-1 gates = Whh1*h1 + Wx*x + b, act1, h1w store ----
#pragma unroll
    for (int mb = 0; mb < 4; ++mb) {
      const int p = 16*mb + cl;
      const f16x8 ax  = *(const f16x8*)(xsr + p*40 + qd*8);
      const f16x8 ah0 = *(const f16x8*)(h1r + p*72 + qd*8);
      const f16x8 ah1 = *(const f16x8*)(h1r + p*72 + 32 + qd*8);
      f32x4 acc[4];
#pragma unroll
      for (int P = 0; P < 4; ++P) {
        acc[P] = (f32x4){ bxr[P], bxr[P], bxr[P], bxr[P] };
        acc[P] = __builtin_amdgcn_mfma_f32_16x16x32_f16(ah0, whh1f[P][0], acc[P], 0, 0, 0);
        acc[P] = __builtin_amdgcn_mfma_f32_16x16x32_f16(ah1, whh1f[P][1], acc[P], 0, 0, 0);
        acc[P] = __builtin_amdgcn_mfma_f32_16x16x32_f16(ax,  wxf[P],      acc[P], 0, 0, 0);
      }
#pragma unroll
      for (int r = 0; r < 4; ++r) {
        const float hn = lstm_act(acc[0][r], acc[1][r], acc[2][r], acc[3][r],
                                  c1s[mb][r]);
        h1w[(16*mb + 4*qd + r)*72 + 16*wv + cl] = (f16)hn;
      }
    }

    // ---- batch2 loads (w21 + whh2): after batch1's last use ----
    __builtin_amdgcn_sched_barrier(0);
    f16x8 w21f[4][2], whh2f[4][2];
    {
      const unsigned char* wsl = ws;
      asm volatile("" : "+s"(wsl));
      const f16x8* w21B = (const f16x8*)(wsl + WS_W21F);
      const f16x8* w22B = (const f16x8*)(wsl + WS_WHH2F);
#pragma unroll
      for (int P = 0; P < 4; ++P) {
        w21f[P][0]  = w21B[hh_i + P*128];
        w21f[P][1]  = w21B[hh_i + P*128 + 64];
        whh2f[P][0] = w22B[hh_i + P*128];
        whh2f[P][1] = w22B[hh_i + P*128 + 64];
      }
    }

    // ---- store prefetched x_{t+1} ----
    if (t + 1 < TT) {
      f16* xsw = xs[(t + 1) & 1];
      f16x8 v;
#pragma unroll
      for (int j = 0; j < 8; ++j) v[j] = (f16)xr[j];
      *(f16x8*)(xsw + sp*40 + cb) = v;
    }
    __syncthreads();

    // ---- phase B: layer-2 gates = W21*h1_new + Whh2*h2 + b, act2 ----
#pragma unroll
    for (int mb = 0; mb < 4; ++mb) {
      const int p = 16*mb + cl;
      const f16x8 an0 = *(const f16x8*)(h1w + p*72 + qd*8);
      const f16x8 an1 = *(const f16x8*)(h1w + p*72 + 32 + qd*8);
      const f16x8 a20 = *(const f16x8*)(h2r + p*72 + qd*8);
      const f16x8 a21 = *(const f16x8*)(h2r + p*72 + 32 + qd*8);
      f32x4 acc[4];
#pragma unroll
      for (int P = 0; P < 4; ++P) {
        acc[P] = (f32x4){ b2r[P], b2r[P], b2r[P], b2r[P] };
        acc[P] = __builtin_amdgcn_mfma_f32_16x16x32_f16(an0, w21f[P][0],  acc[P], 0, 0, 0);
        acc[P] = __builtin_amdgcn_mfma_f32_16x16x32_f16(an1, w21f[P][1],  acc[P], 0, 0, 0);
        acc[P] = __builtin_amdgcn_mfma_f32_16x16x32_f16(a20, whh2f[P][0], acc[P], 0, 0, 0);
        acc[P] = __builtin_amdgcn_mfma_f32_16x16x32_f16(a21, whh2f[P][1], acc[P], 0, 0, 0);
      }
#pragma unroll
      for (int r = 0; r < 4; ++r) {
        const float hn = lstm_act(acc[0][r], acc[1][r], acc[2][r], acc[3][r],
                                  c2s[mb][r]);
        h2w[(16*mb + 4*qd + r)*72 + 16*wv + cl] = (f16)hn;
      }
    }

    // ---- reload batch1 for t+1 (hidden under act2 latency) ----
    __builtin_amdgcn_sched_barrier(0);
    if (t + 1 < TT) {
      const unsigned char* wsl = ws;
      asm volatile("" : "+s"(wsl));
      const f16x8* wxB = (const f16x8*)(wsl + WS_WXF);
      const f16x8* h1B = (const f16x8*)(wsl + WS_WHH1F);
#pragma unroll
      for (int P = 0; P < 4; ++P) {
        wxf[P]      = wxB[wx_i + P*64];
        whh1f[P][0] = h1B[hh_i + P*128];
        whh1f[P][1] = h1B[hh_i + P*128 + 64];
      }
    }
    __syncthreads();
  }

  // ---- head epilogue: out[p] = bhead + sum_k h2[p][k] * wh[k] ----
  if (tid < 64) {
    const float* wh = (const float*)(ws + WS_WH);
    const f16* row = &h2buf[0][tid * 72];   // final h2 lives in buffer 0
    float s = *((const float*)(ws + WS_BH));
#pragma unroll
    for (int k = 0; k < 64; ++k) s += (float)row[k] * wh[k];
    out[gpix + tid] = s;
  }
}

extern "C" void kernel_launch(void* const* d_in, const int* in_sizes, int n_in,
                              void* d_out, int out_size, void* d_ws, size_t ws_size,
                              hipStream_t stream) {
  const float* x      = (const float*)d_in[0];
  const float* W_red  = (const float*)d_in[1];
  const float* b_red  = (const float*)d_in[2];
  const float* Wih1   = (const float*)d_in[3];
  const float* Whh1   = (const float*)d_in[4];
  const float* bih1   = (const float*)d_in[5];
  const float* bhh1   = (const float*)d_in[6];
  const float* Wc1    = (const float*)d_in[7];
  const float* bc1    = (const float*)d_in[8];
  const float* Wih2   = (const float*)d_in[9];
  const float* Whh2   = (const float*)d_in[10];
  const float* bih2   = (const float*)d_in[11];
  const float* bhh2   = (const float*)d_in[12];
  const float* Wc2    = (const float*)d_in[13];
  const float* bc2    = (const float*)d_in[14];
  const float* W_head = (const float*)d_in[15];
  const float* b_head = (const float*)d_in[16];

  prep_kernel<<<256, 64, 0, stream>>>(W_red, b_red, Wih1, Whh1, bih1, bhh1,
                                      Wc1, bc1, Wih2, Whh2, bih2, bhh2,
                                      Wc2, bc2, W_head, b_head,
                                      (unsigned char*)d_ws);
  convlstm_main<<<2048, 256, 0, stream>>>(x, (const unsigned char*)d_ws,
                                          (float*)d_out);
}

// Round 8
// 533.794 us; speedup vs baseline: 1.4924x; 1.4869x over previous
//
#include <hip/hip_runtime.h>

typedef _Float16 f16;
typedef _Float16 f16x8 __attribute__((ext_vector_type(8)));
typedef float f32x4 __attribute__((ext_vector_type(4)));

#define CIN 28
#define TT 8
#define HW 16384

// gate pre-scales folded into weights: i,f,o rows scaled by -log2e so
// exp2(acc)=e^{-x}, sig(x)=1/(1+E); g rows scaled by +2log2e so tanh=(E-1)/(E+1)
#define S_SIG  (-1.44269504088896341f)
#define S_TANH ( 2.88539008177792681f)

// workspace layout (bytes) — weights stored in FRAGMENT ORDER so each wave's
// per-step reload is a fully-coalesced 1KB global_load_dwordx4 burst (L2-hot).
#define WS_WXF    0        // f16 [wv*4+P][lane][8]            16KB
#define WS_WHH1F  16384    // f16 [(wv*4+P)*2+half][lane][8]   32KB
#define WS_W21F   49152    // 32KB
#define WS_WHH2F  81920    // 32KB
#define WS_BX     114688   // f32 [256]
#define WS_B2     115712   // f32 [256]
#define WS_WH     116736   // f32 [64]
#define WS_BH     116992   // f32 [1]

// Fused LSTM activation: 5 exp2 + 2 rcp (f-gate rcp merged into the i*g rcp).
__device__ __forceinline__ float lstm_act(float gi, float gf, float gg, float go,
                                          float& c) {
  const float Ei = __builtin_amdgcn_exp2f(gi);
  const float Ef = __builtin_amdgcn_exp2f(gf);
  const float Eg = __builtin_amdgcn_exp2f(gg);
  const float Eo = __builtin_amdgcn_exp2f(go);
  const float F  = 1.f + Ef;
  const float AG = (1.f + Ei) * (1.f + Eg);
  const float r  = __builtin_amdgcn_rcpf(F * AG);
  const float cn = __builtin_fmaf(c, r * AG, (Eg - 1.f) * (r * F));
  c = cn;
  const float Ec  = __builtin_amdgcn_exp2f(cn * S_TANH);
  const float roc = __builtin_amdgcn_rcpf((1.f + Eo) * (1.f + Ec));
  return (Ec - 1.f) * roc;
}

// AGPR-resident scalar state helpers (r3-proven; forces allocation BEYOND the
// 128 arch-VGPR cap the allocator insists on under waves_per_eu(2,2)).
__device__ __forceinline__ float ag_get(float a) {
  float v; asm("v_accvgpr_read_b32 %0, %1" : "=v"(v) : "a"(a)); return v;
}
__device__ __forceinline__ float ag_put(float v) {
  float a; asm("v_accvgpr_write_b32 %0, %1" : "=a"(a) : "v"(v)); return a;
}

// Parallel prep: 256 blocks (one per gate row g) x 64 threads (one per col k).
// Writes weights in fragment order: P=g>>6, wv=(g>>4)&3, cl=g&15;
// half=k>>5, qd=(k>>3)&3, j=k&7; lane=qd*16+cl.
__global__ __launch_bounds__(64) void prep_kernel(
    const float* __restrict__ W_red, const float* __restrict__ b_red,
    const float* __restrict__ Wih1, const float* __restrict__ Whh1,
    const float* __restrict__ bih1, const float* __restrict__ bhh1,
    const float* __restrict__ Wc1,  const float* __restrict__ bc1,
    const float* __restrict__ Wih2, const float* __restrict__ Whh2,
    const float* __restrict__ bih2, const float* __restrict__ bhh2,
    const float* __restrict__ Wc2,  const float* __restrict__ bc2,
    const float* __restrict__ W_head, const float* __restrict__ b_head,
    unsigned char* __restrict__ ws)
{
  const int g = blockIdx.x;    // 0..255 gate row
  const int k = threadIdx.x;   // 0..63 col
  const int P  = g >> 6, wvv = (g >> 4) & 3, cl = g & 15;
  const int half = k >> 5, qd = (k >> 3) & 3, j = k & 7;
  const int lane = qd * 16 + cl;

  f16* WXF   = (f16*)(ws + WS_WXF);
  f16* WHH1F = (f16*)(ws + WS_WHH1F);
  f16* W21F  = (f16*)(ws + WS_W21F);
  f16* WHH2F = (f16*)(ws + WS_WHH2F);
  float* BX  = (float*)(ws + WS_BX);
  float* B2  = (float*)(ws + WS_B2);
  float* WHp = (float*)(ws + WS_WH);
  float* BHp = (float*)(ws + WS_BH);

  const float sc = (P == 2) ? S_TANH : S_SIG;  // g-gate rows use tanh scale

  // Wx[g][k] = Wih1[g,:] @ W_red[:,k]  (k < CIN), + u/v denorm fold
  float wxv = 0.f;
  if (k < CIN) {
    float s = 0.f;
    for (int r = 0; r < 24; ++r) s += Wih1[g*24 + r] * W_red[r*28 + k];
    wxv = s;
  }
  const float wx11 = __shfl(wxv, 11, 64);
  const float wx12 = __shfl(wxv, 12, 64);
  if (k == 11) wxv *= 0.15f;   // SD_U
  if (k == 12) wxv *= 0.12f;   // SD_V
  if (k < 32)
    WXF[((wvv*4 + P)*64 + lane)*8 + j] = (f16)(wxv * sc);

  const int fidx = (((wvv*4 + P)*2 + half)*64 + lane)*8 + j;
  WHH1F[fidx] = (f16)(Whh1[g*64 + k] * sc);
  WHH2F[fidx] = (f16)(Whh2[g*64 + k] * sc);
  {
    float s = 0.f;
    for (int m = 0; m < 64; ++m) s += Wih2[g*64 + m] * Wc1[m*64 + k];
    W21F[fidx] = (f16)(s * sc);
  }

  if (k == 0) {
    float bx = bih1[g] + bhh1[g];
    for (int r = 0; r < 24; ++r) bx += Wih1[g*24 + r] * b_red[r];
    bx += wx11 * 0.02f + wx12 * (-0.01f);   // MU_U, MU_V
    BX[g] = bx * sc;
    float b2v = bih2[g] + bhh2[g];
    for (int m = 0; m < 64; ++m) b2v += Wih2[g*64 + m] * bc1[m];
    B2[g] = b2v * sc;
  }
  if (g == 0) {
    float s = 0.f;
    for (int m = 0; m < 64; ++m) s += W_head[m] * Wc2[m*64 + k];
    WHp[k] = s;
    if (k == 0) {
      float s2 = b_head[0];
      for (int m = 0; m < 64; ++m) s2 += W_head[m] * bc2[m];
      BHp[0] = s2;
    }
  }
}

// 64 pixels/block, 4 waves; wave w owns hidden cols [16w,16w+16) x 4 gates.
// Weights TRANSIENT (reloaded L2-hot each step, frag-ordered, coalesced).
// waves_per_eu(2,2): empirically pins arch-VGPRs at 128 with sane allocation
// (r2-r5); c1/c2 cell state + x prefetch pushed to AGPRs via explicit asm
// (40 AGPRs) so arch demand fits 128 with NO scratch. Total 128+40=168
// regs/wave -> 3 waves/SIMD; LDS 47104 -> 3 blocks/CU: 12 waves/CU.
// (r6/r7 failure: waves_per_eu(3) made the allocator target 84 VGPRs ->
// 1.8 GB scratch storm. Never trust the occupancy heuristic; force it.)
__global__ __launch_bounds__(256)
__attribute__((amdgpu_waves_per_eu(2, 2)))
void convlstm_main(
    const float* __restrict__ x, const unsigned char* __restrict__ ws,
    float* __restrict__ out)
{
  __shared__ __align__(16) f16 xs[2][64 * 40];       // [pixel][ch], stride 40
  __shared__ __align__(16) f16 h1buf[2][64 * 72];    // [pixel][hid], stride 72
  __shared__ __align__(16) f16 h2buf[2][64 * 72];

  const int tid  = threadIdx.x;
  const int lane = tid & 63;
  const int wv   = tid >> 6;
  const int cl   = lane & 15;
  const int qd   = lane >> 4;

  // per-thread f16x8 indices into the frag areas
  const int wx_i  = (wv*4)*64 + lane;    // + P*64
  const int hh_i  = wv*512 + lane;       // + P*128 + half*64

  const float* BX = (const float*)(ws + WS_BX);
  const float* B2 = (const float*)(ws + WS_B2);
  float bxr[4], b2r[4];
#pragma unroll
  for (int P = 0; P < 4; ++P) {
    bxr[P] = BX[64*P + 16*wv + cl];
    b2r[P] = B2[64*P + 16*wv + cl];
  }

  // zero t=0 h buffers
  {
    unsigned* z1 = (unsigned*)&h1buf[0][0];
    unsigned* z2 = (unsigned*)&h2buf[0][0];
#pragma unroll
    for (int i = tid; i < 2304; i += 256) { z1[i] = 0u; z2[i] = 0u; }
  }

  const int gpix = blockIdx.x * 64;
  const float* xb = x + (size_t)(gpix >> 14) * (TT * CIN * HW) + (gpix & (HW - 1));

  const int sp = lane;        // staging pixel
  const int cb = wv * 8;      // staging channel base

  // stage x_0
  {
    f16x8 v;
#pragma unroll
    for (int j = 0; j < 8; ++j) {
      const int ch = cb + j;
      v[j] = (ch < CIN) ? (f16)xb[ch*HW + sp] : (f16)0.f;
    }
    *(f16x8*)(&xs[0][sp*40 + cb]) = v;
  }
  __syncthreads();

  float c1s[4][4], c2s[4][4];   // AGPR-homed (ag_get/ag_put only)
#pragma unroll
  for (int a = 0; a < 4; ++a)
#pragma unroll
    for (int b = 0; b < 4; ++b) { c1s[a][b] = ag_put(0.f); c2s[a][b] = ag_put(0.f); }

  // preload batch1 (wx + whh1) for t=0
  f16x8 wxf[4], whh1f[4][2];
  {
    const unsigned char* wsl = ws;
    asm volatile("" : "+s"(wsl));
    const f16x8* wxB = (const f16x8*)(wsl + WS_WXF);
    const f16x8* h1B = (const f16x8*)(wsl + WS_WHH1F);
#pragma unroll
    for (int P = 0; P < 4; ++P) {
      wxf[P]      = wxB[wx_i + P*64];
      whh1f[P][0] = h1B[hh_i + P*128];
      whh1f[P][1] = h1B[hh_i + P*128 + 64];
    }
  }

#pragma unroll 1
  for (int t = 0; t < TT; ++t) {
    // ---- prefetch x_{t+1}; park in AGPRs so it doesn't hold arch VGPRs ----
    float xrA[8];
    if (t + 1 < TT) {
      const float* xt = xb + (size_t)(t + 1) * (CIN * HW);
#pragma unroll
      for (int j = 0; j < 8; ++j) {
        const int ch = cb + j;
        xrA[j] = ag_put((ch < CIN) ? xt[ch*HW + sp] : 0.f);
      }
    }

    const f16* xsr = xs[t & 1];
    const f16* h1r = h1buf[t & 1];
    const f16* h2r = h2buf[t & 1];
    f16* h1w = h1buf[(t + 1) & 1];
    f16* h2w = h2buf[(t + 1) & 1];

    // ---- phase A: layer-1 gates = Whh1*h1 + Wx*x + b, act1, h1w store ----
#pragma unroll
    for (int mb = 0; mb < 4; ++mb) {
      const int p = 16*mb + cl;
      const f16x8 ax  = *(const f16x8*)(xsr + p*40 + qd*8);
      const f16x8 ah0 = *(const f16x8*)(h1r + p*72 + qd*8);
      const f16x8 ah1 = *(const f16x8*)(h1r + p*72 + 32 + qd*8);
      f32x4 acc[4];
#pragma unroll
      for (int P = 0; P < 4; ++P) {
        acc[P] = (f32x4){ bxr[P], bxr[P], bxr[P], bxr[P] };
        acc[P] = __builtin_amdgcn_mfma_f32_16x16x32_f16(ah0, whh1f[P][0], acc[P], 0, 0, 0);
        acc[P] = __builtin_amdgcn_mfma_f32_16x16x32_f16(ah1, whh1f[P][1], acc[P], 0, 0, 0);
        acc[P] = __builtin_amdgcn_mfma_f32_16x16x32_f16(ax,  wxf[P],      acc[P], 0, 0, 0);
      }
#pragma unroll
      for (int r = 0; r < 4; ++r) {
        float c = ag_get(c1s[mb][r]);
        const float hn = lstm_act(acc[0][r], acc[1][r], acc[2][r], acc[3][r], c);
        c1s[mb][r] = ag_put(c);
        h1w[(16*mb + 4*qd + r)*72 + 16*wv + cl] = (f16)hn;
      }
    }

    // ---- batch2 loads (w21 + whh2): after batch1's last use ----
    __builtin_amdgcn_sched_barrier(0);
    f16x8 w21f[4][2], whh2f[4][2];
    {
      const unsigned char* wsl = ws;
      asm volatile("" : "+s"(wsl));
      const f16x8* w21B = (const f16x8*)(wsl + WS_W21F);
      const f16x8* w22B = (const f16x8*)(wsl + WS_WHH2F);
#pragma unroll
      for (int P = 0; P < 4; ++P) {
        w21f[P][0]  = w21B[hh_i + P*128];
        w21f[P][1]  = w21B[hh_i + P*128 + 64];
        whh2f[P][0] = w22B[hh_i + P*128];
        whh2f[P][1] = w22B[hh_i + P*128 + 64];
      }
    }

    // ---- store prefetched x_{t+1} (pull back from AGPRs) ----
    if (t + 1 < TT) {
      f16* xsw = xs[(t + 1) & 1];
      f16x8 v;
#pragma unroll
      for (int j = 0; j < 8; ++j) v[j] = (f16)ag_get(xrA[j]);
      *(f16x8*)(xsw + sp*40 + cb) = v;
    }
    __syncthreads();

    // ---- phase B: layer-2 gates = W21*h1_new + Whh2*h2 + b, act2 ----
#pragma unroll
    for (int mb = 0; mb < 4; ++mb) {
      const int p = 16*mb + cl;
      const f16x8 an0 = *(const f16x8*)(h1w + p*72 + qd*8);
      const f16x8 an1 = *(const f16x8*)(h1w + p*72 + 32 + qd*8);
      const f16x8 a20 = *(const f16x8*)(h2r + p*72 + qd*8);
      const f16x8 a21 = *(const f16x8*)(h2r + p*72 + 32 + qd*8);
      f32x4 acc[4];
#pragma unroll
      for (int P = 0; P < 4; ++P) {
        acc[P] = (f32x4){ b2r[P], b2r[P], b2r[P], b2r[P] };
        acc[P] = __builtin_amdgcn_mfma_f32_16x16x32_f16(an0, w21f[P][0],  acc[P], 0, 0, 0);
        acc[P] = __builtin_amdgcn_mfma_f32_16x16x32_f16(an1, w21f[P][1],  acc[P], 0, 0, 0);
        acc[P] = __builtin_amdgcn_mfma_f32_16x16x32_f16(a20, whh2f[P][0], acc[P], 0, 0, 0);
        acc[P] = __builtin_amdgcn_mfma_f32_16x16x32_f16(a21, whh2f[P][1], acc[P], 0, 0, 0);
      }
#pragma unroll
      for (int r = 0; r < 4; ++r) {
        float c = ag_get(c2s[mb][r]);
        const float hn = lstm_act(acc[0][r], acc[1][r], acc[2][r], acc[3][r], c);
        c2s[mb][r] = ag_put(c);
        h2w[(16*mb + 4*qd + r)*72 + 16*wv + cl] = (f16)hn;
      }
    }

    // ---- reload batch1 for t+1 (hidden under act2 latency) ----
    __builtin_amdgcn_sched_barrier(0);
    if (t + 1 < TT) {
      const unsigned char* wsl = ws;
      asm volatile("" : "+s"(wsl));
      const f16x8* wxB = (const f16x8*)(wsl + WS_WXF);
      const f16x8* h1B = (const f16x8*)(wsl + WS_WHH1F);
#pragma unroll
      for (int P = 0; P < 4; ++P) {
        wxf[P]      = wxB[wx_i + P*64];
        whh1f[P][0] = h1B[hh_i + P*128];
        whh1f[P][1] = h1B[hh_i + P*128 + 64];
      }
    }
    __syncthreads();
  }

  // ---- head epilogue: out[p] = bhead + sum_k h2[p][k] * wh[k] ----
  if (tid < 64) {
    const float* wh = (const float*)(ws + WS_WH);
    const f16* row = &h2buf[0][tid * 72];   // final h2 lives in buffer 0
    float s = *((const float*)(ws + WS_BH));
#pragma unroll
    for (int k = 0; k < 64; ++k) s += (float)row[k] * wh[k];
    out[gpix + tid] = s;
  }
}

extern "C" void kernel_launch(void* const* d_in, const int* in_sizes, int n_in,
                              void* d_out, int out_size, void* d_ws, size_t ws_size,
                              hipStream_t stream) {
  const float* x      = (const float*)d_in[0];
  const float* W_red  = (const float*)d_in[1];
  const float* b_red  = (const float*)d_in[2];
  const float* Wih1   = (const float*)d_in[3];
  const float* Whh1   = (const float*)d_in[4];
  const float* bih1   = (const float*)d_in[5];
  const float* bhh1   = (const float*)d_in[6];
  const float* Wc1    = (const float*)d_in[7];
  const float* bc1    = (const float*)d_in[8];
  const float* Wih2   = (const float*)d_in[9];
  const float* Whh2   = (const float*)d_in[10];
  const float* bih2   = (const float*)d_in[11];
  const float* bhh2   = (const float*)d_in[12];
  const float* Wc2    = (const float*)d_in[13];
  const float* bc2    = (const float*)d_in[14];
  const float* W_head = (const float*)d_in[15];
  const float* b_head = (const float*)d_in[16];

  prep_kernel<<<256, 64, 0, stream>>>(W_red, b_red, Wih1, Whh1, bih1, bhh1,
                                      Wc1, bc1, Wih2, Whh2, bih2, bhh2,
                                      Wc2, bc2, W_head, b_head,
                                      (unsigned char*)d_ws);
  convlstm_main<<<2048, 256, 0, stream>>>(x, (const unsigned char*)d_ws,
                                          (float*)d_out);
}